// Round 4
// baseline (433.703 us; speedup 1.0000x reference)
//
#include <hip/hip_runtime.h>
#include <math.h>

// ---- problem constants (from reference setup_inputs) ----
constexpr int kNB   = 8;
constexpr int kNT   = 5;
constexpr int kNA   = 2;
constexpr int kNDET = 2;
constexpr int kNREG = 6;
constexpr int kNH   = 320;
constexpr int kNW   = 320;
constexpr int kHW   = kNH * kNW;          // 102400
constexpr int kHW4  = kHW / 4;            // 25600 float4-quads per plane
constexpr int kDetCh = kNA * kNDET * kNT; // 20 channels
constexpr int kRegCh = kNA * kNREG * kNT; // 60 channels
constexpr int kBoxFloats = kNB * kNT * kNA * kHW * 6; // 49,152,000
constexpr int kQuads = kNB * kNT * kHW4;  // 1,024,000 threads

__device__ __forceinline__ float sigmoidf_(float x) {
    return 1.0f / (1.0f + expf(-x));
}

__global__ __launch_bounds__(256) void fafe_predict(
    const float* __restrict__ det, const float* __restrict__ reg,
    float* __restrict__ out)
{
    const int idx = blockIdx.x * blockDim.x + threadIdx.x;
    if (idx >= kQuads) return;

    const int q  = idx % kHW4;   // quad index within a (b,ch) plane
    const int bt = idx / kHW4;   // b*nT + t
    const int t  = bt % kNT;
    const int b  = bt / kNT;
    const int s  = q * 4;        // spatial element index (h*nW + w)
    const int wb = s % kNW;      // w of first element (row-safe: 320 % 4 == 0)

    const float4* det4 = reinterpret_cast<const float4*>(det);
    const float4* reg4 = reinterpret_cast<const float4*>(reg);
    float4* out4 = reinterpret_cast<float4*>(out);

    constexpr int kPlane6o4  = kHW * 6 / 4;      // 153600 float4 per (bt,a) box plane
    constexpr int kMaskBase4 = kBoxFloats / 4;   // 12,288,000 float4 offset of mask

    // ---------------- phase 1: detection -> probs + masks ----------------
    // det channel = a*NDET*NT + c*NT + t = a*10 + c*5 + t
    const int dbase = (b * kDetCh + t) * kHW4 + q;
    const float4 d00 = det4[dbase + 0 * kHW4];   // a=0,c=0
    const float4 d01 = det4[dbase + 5 * kHW4];   // a=0,c=1
    const float4 d10 = det4[dbase + 10 * kHW4];  // a=1,c=0
    const float4 d11 = det4[dbase + 15 * kHW4];  // a=1,c=1

    float p0[4], p1[4];
    float4 m0v, m1v;
    {
        const float* x00 = reinterpret_cast<const float*>(&d00);
        const float* x01 = reinterpret_cast<const float*>(&d01);
        const float* x10 = reinterpret_cast<const float*>(&d10);
        const float* x11 = reinterpret_cast<const float*>(&d11);
        float* pm0 = reinterpret_cast<float*>(&m0v);
        float* pm1 = reinterpret_cast<float*>(&m1v);
#pragma unroll
        for (int j = 0; j < 4; ++j) {
            // 2-class softmax channel 1 == sigmoid(x1 - x0)
            p0[j] = sigmoidf_(x01[j] - x00[j]);
            p1[j] = sigmoidf_(x11[j] - x10[j]);
            const bool best1 = p1[j] > p0[j];  // argmax, ties -> anchor 0
            pm0[j] = (p0[j] > 0.7f && !best1) ? 1.0f : 0.0f;
            pm1[j] = (p1[j] > 0.7f && best1) ? 1.0f : 0.0f;
        }
    }
    out4[kMaskBase4 + (bt * 2 + 0) * kHW4 + q] = m0v;
    out4[kMaskBase4 + (bt * 2 + 1) * kHW4 + q] = m1v;

    // ---------------- phase 2+3: regression per anchor ----------------
    // reg channel = a*NREG*NT + r*NT + t = a*30 + r*5 + t
    const int rbase = (b * kRegCh + t) * kHW4 + q;
#pragma unroll
    for (int a = 0; a < kNA; ++a) {
        const int ab = rbase + a * 30 * kHW4;
        const float4 r0 = reg4[ab + 0 * kHW4];
        const float4 r1 = reg4[ab + 5 * kHW4];
        const float4 r2 = reg4[ab + 10 * kHW4];
        const float4 r3 = reg4[ab + 15 * kHW4];
        const float4 r4 = reg4[ab + 20 * kHW4];
        const float4 r5 = reg4[ab + 25 * kHW4];

        const float a_l = (a == 0) ? 3.9f : 1.0f;
        const float a_w = (a == 0) ? 1.6f : 0.6f;
        const float* pp = (a == 0) ? p0 : p1;

        const float* x0 = reinterpret_cast<const float*>(&r0);
        const float* x1 = reinterpret_cast<const float*>(&r1);
        const float* x2 = reinterpret_cast<const float*>(&r2);
        const float* x3 = reinterpret_cast<const float*>(&r3);
        const float* x4 = reinterpret_cast<const float*>(&r4);
        const float* x5 = reinterpret_cast<const float*>(&r5);

        alignas(16) float boxes[24];
#pragma unroll
        for (int j = 0; j < 4; ++j) {
            const float gw  = (float)(wb + j);   // grid_x = w * 0.2f
            const float gwm = gw - 160.0f;       // grid_y = (w-160) * 0.2f
            boxes[j*6 + 0] = sigmoidf_(x0[j]) * 0.2f + gw  * 0.2f;
            boxes[j*6 + 1] = sigmoidf_(x1[j]) * 0.2f + gwm * 0.2f;
            boxes[j*6 + 2] = expf(x3[j]) * a_l;  // l from t_l = reg[...,3]
            boxes[j*6 + 3] = expf(x2[j]) * a_w;  // w from t_w = reg[...,2]
            boxes[j*6 + 4] = atan2f(x5[j], x4[j]);
            boxes[j*6 + 5] = pp[j];
        }

        // boxes_scores layout (b,t,a,h,w,6): 24 contiguous floats per (quad,anchor)
        const int ob = (bt * 2 + a) * kPlane6o4 + q * 6;
        const float4* bv = reinterpret_cast<const float4*>(boxes);
#pragma unroll
        for (int m = 0; m < 6; ++m) out4[ob + m] = bv[m];
    }
}

extern "C" void kernel_launch(void* const* d_in, const int* in_sizes, int n_in,
                              void* d_out, int out_size, void* d_ws, size_t ws_size,
                              hipStream_t stream) {
    const float* det = (const float*)d_in[0];
    const float* reg = (const float*)d_in[1];
    float* out = (float*)d_out;

    constexpr int kBlock = 256;
    constexpr int kGrid = (kQuads + kBlock - 1) / kBlock;  // 4000 blocks
    fafe_predict<<<kGrid, kBlock, 0, stream>>>(det, reg, out);
}

// Round 6
// 406.116 us; speedup vs baseline: 1.0679x; 1.0679x over previous
//
#include <hip/hip_runtime.h>
#include <math.h>

// ---- problem constants (from reference setup_inputs) ----
constexpr int kNB   = 8;
constexpr int kNT   = 5;
constexpr int kNA   = 2;
constexpr int kNDET = 2;
constexpr int kNREG = 6;
constexpr int kNH   = 320;
constexpr int kNW   = 320;
constexpr int kHW   = kNH * kNW;          // 102400
constexpr int kHW4  = kHW / 4;            // 25600 float4-quads per plane
constexpr int kDetCh = kNA * kNDET * kNT; // 20 channels
constexpr int kRegCh = kNA * kNREG * kNT; // 60 channels
constexpr int kBoxFloats = kNB * kNT * kNA * kHW * 6; // 49,152,000
constexpr int kQuads = kNB * kNT * kHW4;  // 1,024,000 (one thread per 4 positions)
constexpr int kBlock = 256;
constexpr int kGrid  = kQuads / kBlock;   // 4000 (kHW4 % kBlock == 0: no plane straddle)

typedef float f32x4 __attribute__((ext_vector_type(4)));

__device__ __forceinline__ float sigmoidf_(float x) {
    return 1.0f / (1.0f + expf(-x));
}

__global__ __launch_bounds__(256) void fafe_predict(
    const float* __restrict__ det, const float* __restrict__ reg,
    float* __restrict__ out)
{
    // 24 KB SoA tile: component c of local position p at ldsf[c*1024 + p].
    // Written as float4 (4 consecutive p per thread) -> lane-contiguous
    // ds_write_b128, conflict-free.
    __shared__ f32x4 lds4[6 * 256];
    float* ldsf = reinterpret_cast<float*>(lds4);

    const int tid = threadIdx.x;
    const int idx = blockIdx.x * kBlock + tid;   // quad id
    const int q   = idx % kHW4;                  // quad within (b,t) plane
    const int bt  = idx / kHW4;
    const int t   = bt % kNT;
    const int b   = bt / kNT;
    const int wb  = (q * 4) % kNW;               // w of first elem (320 % 4 == 0)
    const int qbase = q - tid;                   // block's first quad in plane

    const float4* det4 = reinterpret_cast<const float4*>(det);
    const float4* reg4 = reinterpret_cast<const float4*>(reg);
    float4* out4 = reinterpret_cast<float4*>(out);

    constexpr int kPlane6o4  = kHW * 6 / 4;      // 153600 float4 per (bt,a) box plane
    constexpr int kMaskBase4 = kBoxFloats / 4;   // float4 offset of mask region

    // ---------------- phase 1: detection -> probs + masks ----------------
    // det channel = a*NDET*NT + c*NT + t = a*10 + c*5 + t
    const int dbase = (b * kDetCh + t) * kHW4 + q;
    const float4 d00 = det4[dbase + 0  * kHW4];  // a=0,c=0
    const float4 d01 = det4[dbase + 5  * kHW4];  // a=0,c=1
    const float4 d10 = det4[dbase + 10 * kHW4];  // a=1,c=0
    const float4 d11 = det4[dbase + 15 * kHW4];  // a=1,c=1

    float p0[4], p1[4];
    f32x4 m0v, m1v;
    {
        const float* x00 = reinterpret_cast<const float*>(&d00);
        const float* x01 = reinterpret_cast<const float*>(&d01);
        const float* x10 = reinterpret_cast<const float*>(&d10);
        const float* x11 = reinterpret_cast<const float*>(&d11);
#pragma unroll
        for (int j = 0; j < 4; ++j) {
            // 2-class softmax channel 1 == sigmoid(x1 - x0)
            p0[j] = sigmoidf_(x01[j] - x00[j]);
            p1[j] = sigmoidf_(x11[j] - x10[j]);
            const bool best1 = p1[j] > p0[j];    // argmax, ties -> anchor 0
            m0v[j] = (p0[j] > 0.7f && !best1) ? 1.0f : 0.0f;
            m1v[j] = (p1[j] > 0.7f && best1) ? 1.0f : 0.0f;
        }
    }
    // masks: lane-consecutive float4 -> already coalesced; nontemporal
    __builtin_nontemporal_store(
        m0v, reinterpret_cast<f32x4*>(&out4[kMaskBase4 + (bt * 2 + 0) * kHW4 + q]));
    __builtin_nontemporal_store(
        m1v, reinterpret_cast<f32x4*>(&out4[kMaskBase4 + (bt * 2 + 1) * kHW4 + q]));

    // ---------------- phase 2: regression, LDS-transposed stores ----------------
    // reg channel = a*NREG*NT + r*NT + t = a*30 + r*5 + t
    const int rbase = (b * kRegCh + t) * kHW4 + q;
#pragma unroll
    for (int a = 0; a < kNA; ++a) {
        const int ab = rbase + a * 30 * kHW4;
        const float4 r0 = reg4[ab + 0  * kHW4];
        const float4 r1 = reg4[ab + 5  * kHW4];
        const float4 r2 = reg4[ab + 10 * kHW4];
        const float4 r3 = reg4[ab + 15 * kHW4];
        const float4 r4 = reg4[ab + 20 * kHW4];
        const float4 r5 = reg4[ab + 25 * kHW4];

        const float a_l = (a == 0) ? 3.9f : 1.0f;
        const float a_w = (a == 0) ? 1.6f : 0.6f;
        const float* pp = (a == 0) ? p0 : p1;

        const float* x0 = reinterpret_cast<const float*>(&r0);
        const float* x1 = reinterpret_cast<const float*>(&r1);
        const float* x2 = reinterpret_cast<const float*>(&r2);
        const float* x3 = reinterpret_cast<const float*>(&r3);
        const float* x4 = reinterpret_cast<const float*>(&r4);
        const float* x5 = reinterpret_cast<const float*>(&r5);

        f32x4 cx, cy, cl, cw, cg, cs;   // per-component vectors over j=0..3
#pragma unroll
        for (int j = 0; j < 4; ++j) {
            const float gw  = (float)(wb + j);   // grid_x = w * 0.2f
            const float gwm = gw - 160.0f;       // grid_y = (w-160) * 0.2f
            cx[j] = sigmoidf_(x0[j]) * 0.2f + gw  * 0.2f;
            cy[j] = sigmoidf_(x1[j]) * 0.2f + gwm * 0.2f;
            cl[j] = expf(x3[j]) * a_l;           // l from t_l = reg[...,3]
            cw[j] = expf(x2[j]) * a_w;           // w from t_w = reg[...,2]
            cg[j] = atan2f(x5[j], x4[j]);
            cs[j] = pp[j];
        }

        if (a == 1) __syncthreads();  // phase-B reads of anchor 0 must finish
        // SoA write: comp c, positions tid*4..tid*4+3 -> float4 index c*256+tid
        lds4[0 * 256 + tid] = cx;
        lds4[1 * 256 + tid] = cy;
        lds4[2 * 256 + tid] = cl;
        lds4[3 * 256 + tid] = cw;
        lds4[4 * 256 + tid] = cg;
        lds4[5 * 256 + tid] = cs;
        __syncthreads();

        // phase B: stream 1536 float4 (24 KB) out, lane-consecutive = coalesced
        const int obase = (bt * 2 + a) * kPlane6o4 + qbase * 6;
#pragma unroll
        for (int k = 0; k < 6; ++k) {
            const int o  = k * 256 + tid;        // float4 index within region
            const int f0 = 4 * o;                // first float index
            f32x4 v;
#pragma unroll
            for (int e = 0; e < 4; ++e) {
                const int f = f0 + e;            // AoS float idx = pos*6 + comp
                v[e] = ldsf[(f % 6) * 1024 + (f / 6)];
            }
            __builtin_nontemporal_store(
                v, reinterpret_cast<f32x4*>(&out4[obase + o]));
        }
    }
}

extern "C" void kernel_launch(void* const* d_in, const int* in_sizes, int n_in,
                              void* d_out, int out_size, void* d_ws, size_t ws_size,
                              hipStream_t stream) {
    const float* det = (const float*)d_in[0];
    const float* reg = (const float*)d_in[1];
    float* out = (float*)d_out;
    fafe_predict<<<kGrid, kBlock, 0, stream>>>(det, reg, out);
}